// Round 1
// baseline (1053.543 us; speedup 1.0000x reference)
//
#include <hip/hip_runtime.h>

#define NN 100000
#define NE 1600000
#define NG 256
#define FIN 10
#define HID 128
#define NB 64   // pool buckets per graph to spread atomic contention

// ---------------- kernels ----------------

__global__ void k_init(float* __restrict__ deg, float* __restrict__ pool,
                       float* __restrict__ cnt) {
  int i = blockIdx.x * blockDim.x + threadIdx.x;
  if (i < NN) deg[i] = 1.0f;                    // self-loop weight pre-added
  if (i < NG * NB) { pool[i] = 0.0f; cnt[i] = 0.0f; }
}

__global__ void k_deg(const int* __restrict__ col, const float* __restrict__ w,
                      float* __restrict__ deg) {
  int e = blockIdx.x * blockDim.x + threadIdx.x;
  if (e < NE) atomicAdd(&deg[col[e]], w[e]);
}

// dinv[n] = rsqrt(deg[n]); ax[n][:] initialized with self-loop term dinv^2 * x[n][:]
__global__ void k_dinv_ax(const float* __restrict__ deg, const float* __restrict__ x,
                          float* __restrict__ dinv, float* __restrict__ ax) {
  int n = blockIdx.x * blockDim.x + threadIdx.x;
  if (n < NN) {
    float d = deg[n];
    float di = (d > 0.f) ? rsqrtf(d) : 0.f;
    dinv[n] = di;
    float d2 = di * di;
#pragma unroll
    for (int f = 0; f < FIN; ++f) ax[n * FIN + f] = d2 * x[n * FIN + f];
  }
}

// ax[dst][:] += norm_e * x[src][:]   (10 features)
__global__ void k_agg1(const int* __restrict__ row, const int* __restrict__ col,
                       const float* __restrict__ w, const float* __restrict__ dinv,
                       const float* __restrict__ x, float* __restrict__ ax) {
  int e = blockIdx.x * blockDim.x + threadIdx.x;
  if (e < NE) {
    int r = row[e], c = col[e];
    float nm = dinv[r] * w[e] * dinv[c];
#pragma unroll
    for (int f = 0; f < FIN; ++f)
      atomicAdd(&ax[c * FIN + f], nm * x[r * FIN + f]);
  }
}

// v = W2 @ Wlin  (128), c = b2 . Wlin + blin
__global__ void k_v(const float* __restrict__ W2, const float* __restrict__ Wlin,
                    const float* __restrict__ b2, const float* __restrict__ blin,
                    float* __restrict__ v, float* __restrict__ cc) {
  int i = threadIdx.x;  // 128 threads
  float acc = 0.f;
  for (int o = 0; o < HID; ++o) acc += W2[i * HID + o] * Wlin[o];
  v[i] = acc;
  if (i == 0) {
    float b = blin[0];
    for (int o = 0; o < HID; ++o) b += b2[o] * Wlin[o];
    cc[0] = b;
  }
}

// s[n] = relu(ax[n] @ W1 + b1) . v ; also self-loop pool contribution and counts
__global__ void k_s(const float* __restrict__ ax, const float* __restrict__ W1,
                    const float* __restrict__ b1, const float* __restrict__ v,
                    const float* __restrict__ dinv, const int* __restrict__ batch,
                    float* __restrict__ s, float* __restrict__ pool,
                    float* __restrict__ cnt) {
  __shared__ float W1s[FIN * HID];
  __shared__ float b1s[HID];
  __shared__ float vs[HID];
  for (int i = threadIdx.x; i < FIN * HID; i += blockDim.x) W1s[i] = W1[i];
  if (threadIdx.x < HID) { b1s[threadIdx.x] = b1[threadIdx.x]; vs[threadIdx.x] = v[threadIdx.x]; }
  __syncthreads();
  int n = blockIdx.x * blockDim.x + threadIdx.x;
  if (n < NN) {
    float axr[FIN];
#pragma unroll
    for (int f = 0; f < FIN; ++f) axr[f] = ax[n * FIN + f];
    float acc = 0.f;
    for (int h = 0; h < HID; ++h) {
      float t = b1s[h];
#pragma unroll
      for (int f = 0; f < FIN; ++f) t += axr[f] * W1s[f * HID + h];
      acc += fmaxf(t, 0.f) * vs[h];
    }
    s[n] = acc;
    float di = dinv[n];
    int g = batch[n];
    int bk = threadIdx.x & (NB - 1);
    atomicAdd(&pool[g * NB + bk], di * di * acc);  // self-loop edge n->n
    atomicAdd(&cnt[g * NB + bk], 1.0f);
  }
}

// pool[batch[dst]] += norm_e * s[src]
__global__ void k_pool_e(const int* __restrict__ row, const int* __restrict__ col,
                         const float* __restrict__ w, const float* __restrict__ dinv,
                         const float* __restrict__ s, const int* __restrict__ batch,
                         float* __restrict__ pool) {
  int e = blockIdx.x * blockDim.x + threadIdx.x;
  if (e < NE) {
    int r = row[e], c = col[e];
    float nm = dinv[r] * w[e] * dinv[c];
    atomicAdd(&pool[batch[c] * NB + (threadIdx.x & (NB - 1))], nm * s[r]);
  }
}

__global__ void k_final(const float* __restrict__ pool, const float* __restrict__ cnt,
                        const float* __restrict__ cc, float* __restrict__ out) {
  int g = blockIdx.x * blockDim.x + threadIdx.x;
  if (g < NG) {
    float ps = 0.f, cs = 0.f;
    for (int b = 0; b < NB; ++b) { ps += pool[g * NB + b]; cs += cnt[g * NB + b]; }
    out[g] = ps / fmaxf(cs, 1.0f) + cc[0];
  }
}

// ---------------- launch ----------------

extern "C" void kernel_launch(void* const* d_in, const int* in_sizes, int n_in,
                              void* d_out, int out_size, void* d_ws, size_t ws_size,
                              hipStream_t stream) {
  const float* x     = (const float*)d_in[0];
  const int*   ei    = (const int*)d_in[1];   // [2][NE]: row=src, col=dst
  const float* w     = (const float*)d_in[2];
  const int*   batch = (const int*)d_in[3];
  const float* W1    = (const float*)d_in[4];
  const float* b1    = (const float*)d_in[5];
  const float* W2    = (const float*)d_in[6];
  const float* b2    = (const float*)d_in[7];
  const float* Wlin  = (const float*)d_in[8];
  const float* blin  = (const float*)d_in[9];
  float* out = (float*)d_out;

  const int* row = ei;
  const int* col = ei + NE;

  // workspace layout (floats)
  float* ws   = (float*)d_ws;
  float* deg  = ws;                 // NN
  float* dinv = deg + NN;           // NN
  float* ax   = dinv + NN;          // NN*FIN
  float* s    = ax + (size_t)NN * FIN;  // NN
  float* v    = s + NN;             // HID
  float* cc   = v + HID;            // 1
  float* pool = cc + 1;             // NG*NB
  float* cnt  = pool + NG * NB;     // NG*NB

  const int B = 256;
  const int gN = (NN + B - 1) / B;
  const int gE = (NE + B - 1) / B;

  hipLaunchKernelGGL(k_init, dim3(gN), dim3(B), 0, stream, deg, pool, cnt);
  hipLaunchKernelGGL(k_deg, dim3(gE), dim3(B), 0, stream, col, w, deg);
  hipLaunchKernelGGL(k_dinv_ax, dim3(gN), dim3(B), 0, stream, deg, x, dinv, ax);
  hipLaunchKernelGGL(k_agg1, dim3(gE), dim3(B), 0, stream, row, col, w, dinv, x, ax);
  hipLaunchKernelGGL(k_v, dim3(1), dim3(HID), 0, stream, W2, Wlin, b2, blin, v, cc);
  hipLaunchKernelGGL(k_s, dim3(gN), dim3(B), 0, stream, ax, W1, b1, v, dinv, batch,
                     s, pool, cnt);
  hipLaunchKernelGGL(k_pool_e, dim3(gE), dim3(B), 0, stream, row, col, w, dinv, s,
                     batch, pool);
  hipLaunchKernelGGL(k_final, dim3(1), dim3(B), 0, stream, pool, cnt, cc, out);
}

// Round 2
// 292.564 us; speedup vs baseline: 3.6011x; 3.6011x over previous
//
#include <hip/hip_runtime.h>

#define NN 100000
#define NE 1600000
#define NG 256
#define FIN 10
#define HID 128
#define NB 64          // pool buckets per graph
#define SCAN_B 256
#define NBLK ((NN + SCAN_B - 1) / SCAN_B)   // 391 blocks of block-sums

// ---------------- kernels ----------------

__global__ void k_init(int* __restrict__ cnt_in, float* __restrict__ pool,
                       float* __restrict__ cntg) {
  int i = blockIdx.x * blockDim.x + threadIdx.x;
  if (i < NN) cnt_in[i] = 0;
  if (i < NG * NB) { pool[i] = 0.f; cntg[i] = 0.f; }
}

__global__ void k_count(const int* __restrict__ col, int* __restrict__ cnt_in) {
  int e = blockIdx.x * blockDim.x + threadIdx.x;
  if (e < NE) atomicAdd(&cnt_in[col[e]], 1);
}

// block-local exclusive scan; emit block sums
__global__ void k_scan1(const int* __restrict__ cnt_in, int* __restrict__ offs,
                        int* __restrict__ bsum) {
  __shared__ int tmp[SCAN_B];
  int t = threadIdx.x;
  int i = blockIdx.x * SCAN_B + t;
  int v = (i < NN) ? cnt_in[i] : 0;
  tmp[t] = v; __syncthreads();
  for (int off = 1; off < SCAN_B; off <<= 1) {
    int u = (t >= off) ? tmp[t - off] : 0; __syncthreads();
    tmp[t] += u; __syncthreads();
  }
  if (i < NN) offs[i] = tmp[t] - v;           // exclusive within block
  if (t == SCAN_B - 1) bsum[blockIdx.x] = tmp[t];
}

// single block scans the 391 block sums
__global__ void k_scan2(const int* __restrict__ bsum, int* __restrict__ bpre) {
  __shared__ int tmp[512];
  int t = threadIdx.x;
  int v = (t < NBLK) ? bsum[t] : 0;
  tmp[t] = v; __syncthreads();
  for (int off = 1; off < 512; off <<= 1) {
    int u = (t >= off) ? tmp[t - off] : 0; __syncthreads();
    tmp[t] += u; __syncthreads();
  }
  if (t < NBLK) bpre[t] = tmp[t] - v;
}

__global__ void k_scan3(int* __restrict__ offs, const int* __restrict__ bpre,
                        int* __restrict__ cursor) {
  int i = blockIdx.x * blockDim.x + threadIdx.x;
  if (i < NN) {
    int o = offs[i] + bpre[i / SCAN_B];
    offs[i] = o;
    cursor[i] = o;
  }
}

__global__ void k_fill(const int* __restrict__ row, const int* __restrict__ col,
                       const float* __restrict__ w, int* __restrict__ cursor,
                       int2* __restrict__ elist) {
  int e = blockIdx.x * blockDim.x + threadIdx.x;
  if (e < NE) {
    int c = col[e];
    int p = atomicAdd(&cursor[c], 1);
    elist[p] = make_int2(row[e], __float_as_int(w[e]));
  }
}

// weighted in-degree (+1 self-loop) -> dinv, from contiguous CSR lists
__global__ void k_deg(const int* __restrict__ offs, const int* __restrict__ cnt_in,
                      const int2* __restrict__ elist, float* __restrict__ dinv) {
  int n = blockIdx.x * blockDim.x + threadIdx.x;
  if (n < NN) {
    int o = offs[n], cn = cnt_in[n];
    float d = 1.f;
    for (int k = 0; k < cn; ++k) d += __int_as_float(elist[o + k].y);
    dinv[n] = rsqrtf(d);   // d >= 1 always
  }
}

// xs[n][:] = dinv[n] * x[n][:]
__global__ void k_xs(const float* __restrict__ x, const float* __restrict__ dinv,
                     float* __restrict__ xs) {
  int n = blockIdx.x * blockDim.x + threadIdx.x;
  if (n < NN) {
    float di = dinv[n];
#pragma unroll
    for (int f = 0; f < FIN; ++f) xs[n * FIN + f] = di * x[n * FIN + f];
  }
}

// ax[c][:] = dinv_c * ( xs[c][:] + sum_e w_e * xs[src_e][:] )   — atomic-free
__global__ void k_gax(const int* __restrict__ offs, const int* __restrict__ cnt_in,
                      const int2* __restrict__ elist, const float* __restrict__ xs,
                      const float* __restrict__ dinv, float* __restrict__ ax) {
  int n = blockIdx.x * blockDim.x + threadIdx.x;
  if (n >= NN) return;
  int o = offs[n], cn = cnt_in[n];
  float acc[FIN];
  const float* xc = xs + (size_t)n * FIN;
#pragma unroll
  for (int f = 0; f < FIN; ++f) acc[f] = xc[f];   // self-loop term (pre-scaled)
  for (int k = 0; k < cn; ++k) {
    int2 ew = elist[o + k];
    float wt = __int_as_float(ew.y);
    const float2* xr = (const float2*)(xs + (size_t)ew.x * FIN);  // 8B-aligned
#pragma unroll
    for (int f2 = 0; f2 < FIN / 2; ++f2) {
      float2 p = xr[f2];
      acc[2 * f2]     += wt * p.x;
      acc[2 * f2 + 1] += wt * p.y;
    }
  }
  float dc = dinv[n];
#pragma unroll
  for (int f = 0; f < FIN; ++f) ax[n * FIN + f] = dc * acc[f];
}

// v = W2 @ Wlin, cc = b2 . Wlin + blin
__global__ void k_v(const float* __restrict__ W2, const float* __restrict__ Wlin,
                    const float* __restrict__ b2, const float* __restrict__ blin,
                    float* __restrict__ v, float* __restrict__ cc) {
  int i = threadIdx.x;  // 128 threads
  float acc = 0.f;
  for (int o = 0; o < HID; ++o) acc += W2[i * HID + o] * Wlin[o];
  v[i] = acc;
  if (i == 0) {
    float b = blin[0];
    for (int o = 0; o < HID; ++o) b += b2[o] * Wlin[o];
    cc[0] = b;
  }
}

// ss[n] = dinv[n] * ( relu(ax[n] @ W1 + b1) . v ) ; per-graph node counts
__global__ void k_s(const float* __restrict__ ax, const float* __restrict__ W1,
                    const float* __restrict__ b1, const float* __restrict__ v,
                    const float* __restrict__ dinv, const int* __restrict__ batch,
                    float* __restrict__ ss, float* __restrict__ cntg) {
  __shared__ float W1s[FIN * HID];
  __shared__ float b1s[HID];
  __shared__ float vs[HID];
  for (int i = threadIdx.x; i < FIN * HID; i += blockDim.x) W1s[i] = W1[i];
  if (threadIdx.x < HID) { b1s[threadIdx.x] = b1[threadIdx.x]; vs[threadIdx.x] = v[threadIdx.x]; }
  __syncthreads();
  int n = blockIdx.x * blockDim.x + threadIdx.x;
  if (n < NN) {
    float axr[FIN];
#pragma unroll
    for (int f = 0; f < FIN; ++f) axr[f] = ax[n * FIN + f];
    float acc = 0.f;
    for (int h = 0; h < HID; ++h) {
      float t = b1s[h];
#pragma unroll
      for (int f = 0; f < FIN; ++f) t += axr[f] * W1s[f * HID + h];
      acc += fmaxf(t, 0.f) * vs[h];
    }
    ss[n] = dinv[n] * acc;
    atomicAdd(&cntg[batch[n] * NB + (threadIdx.x & (NB - 1))], 1.0f);
  }
}

// pool[g] += dinv_c * ( ss[c] + sum_e w_e * ss[src_e] )   — one atomic per node
__global__ void k_gpool(const int* __restrict__ offs, const int* __restrict__ cnt_in,
                        const int2* __restrict__ elist, const float* __restrict__ ss,
                        const float* __restrict__ dinv, const int* __restrict__ batch,
                        float* __restrict__ pool) {
  int n = blockIdx.x * blockDim.x + threadIdx.x;
  if (n >= NN) return;
  int o = offs[n], cn = cnt_in[n];
  float acc = ss[n];   // self-loop
  for (int k = 0; k < cn; ++k) {
    int2 ew = elist[o + k];
    acc += __int_as_float(ew.y) * ss[ew.x];
  }
  float t = dinv[n] * acc;
  atomicAdd(&pool[batch[n] * NB + (threadIdx.x & (NB - 1))], t);
}

__global__ void k_final(const float* __restrict__ pool, const float* __restrict__ cntg,
                        const float* __restrict__ cc, float* __restrict__ out) {
  int g = blockIdx.x * blockDim.x + threadIdx.x;
  if (g < NG) {
    float ps = 0.f, cs = 0.f;
    for (int b = 0; b < NB; ++b) { ps += pool[g * NB + b]; cs += cntg[g * NB + b]; }
    out[g] = ps / fmaxf(cs, 1.0f) + cc[0];
  }
}

// ---------------- launch ----------------

extern "C" void kernel_launch(void* const* d_in, const int* in_sizes, int n_in,
                              void* d_out, int out_size, void* d_ws, size_t ws_size,
                              hipStream_t stream) {
  const float* x     = (const float*)d_in[0];
  const int*   ei    = (const int*)d_in[1];
  const float* w     = (const float*)d_in[2];
  const int*   batch = (const int*)d_in[3];
  const float* W1    = (const float*)d_in[4];
  const float* b1    = (const float*)d_in[5];
  const float* W2    = (const float*)d_in[6];
  const float* b2    = (const float*)d_in[7];
  const float* Wlin  = (const float*)d_in[8];
  const float* blin  = (const float*)d_in[9];
  float* out = (float*)d_out;

  const int* row = ei;
  const int* col = ei + NE;

  // workspace layout
  char* p = (char*)d_ws;
  int*   cnt_in = (int*)p;   p += sizeof(int) * NN;
  int*   offs   = (int*)p;   p += sizeof(int) * NN;
  int*   cursor = (int*)p;   p += sizeof(int) * NN;
  int*   bsum   = (int*)p;   p += sizeof(int) * 512;
  int*   bpre   = (int*)p;   p += sizeof(int) * 512;
  int2*  elist  = (int2*)p;  p += sizeof(int2) * NE;
  float* dinv   = (float*)p; p += sizeof(float) * NN;
  float* xs     = (float*)p; p += sizeof(float) * (size_t)NN * FIN;
  float* ax     = (float*)p; p += sizeof(float) * (size_t)NN * FIN;
  float* ss     = (float*)p; p += sizeof(float) * NN;
  float* v      = (float*)p; p += sizeof(float) * HID;
  float* cc     = (float*)p; p += sizeof(float) * 4;
  float* pool   = (float*)p; p += sizeof(float) * NG * NB;
  float* cntg   = (float*)p; p += sizeof(float) * NG * NB;

  const int B = 256;
  const int gN = (NN + B - 1) / B;   // 391
  const int gE = (NE + B - 1) / B;   // 6250

  hipLaunchKernelGGL(k_init,  dim3(gN),   dim3(B), 0, stream, cnt_in, pool, cntg);
  hipLaunchKernelGGL(k_count, dim3(gE),   dim3(B), 0, stream, col, cnt_in);
  hipLaunchKernelGGL(k_scan1, dim3(NBLK), dim3(SCAN_B), 0, stream, cnt_in, offs, bsum);
  hipLaunchKernelGGL(k_scan2, dim3(1),    dim3(512), 0, stream, bsum, bpre);
  hipLaunchKernelGGL(k_scan3, dim3(gN),   dim3(B), 0, stream, offs, bpre, cursor);
  hipLaunchKernelGGL(k_fill,  dim3(gE),   dim3(B), 0, stream, row, col, w, cursor, elist);
  hipLaunchKernelGGL(k_deg,   dim3(gN),   dim3(B), 0, stream, offs, cnt_in, elist, dinv);
  hipLaunchKernelGGL(k_xs,    dim3(gN),   dim3(B), 0, stream, x, dinv, xs);
  hipLaunchKernelGGL(k_gax,   dim3(gN),   dim3(B), 0, stream, offs, cnt_in, elist, xs, dinv, ax);
  hipLaunchKernelGGL(k_v,     dim3(1),    dim3(HID), 0, stream, W2, Wlin, b2, blin, v, cc);
  hipLaunchKernelGGL(k_s,     dim3(gN),   dim3(B), 0, stream, ax, W1, b1, v, dinv, batch, ss, cntg);
  hipLaunchKernelGGL(k_gpool, dim3(gN),   dim3(B), 0, stream, offs, cnt_in, elist, ss, dinv, batch, pool);
  hipLaunchKernelGGL(k_final, dim3(1),    dim3(B), 0, stream, pool, cntg, cc, out);
}

// Round 3
// 198.697 us; speedup vs baseline: 5.3023x; 1.4724x over previous
//
#include <hip/hip_runtime.h>

#define NN 100000
#define NE 1600000
#define NG 256
#define FIN 10
#define XS 12          // padded row stride (floats) for xs/ax -> 48B, float4-aligned
#define HID 128
#define NB 64          // pool buckets per graph
#define SCAN_B 256
#define NBLK ((NN + SCAN_B - 1) / SCAN_B)   // 391

// ---------------- kernels ----------------

__global__ void k_init(int* __restrict__ cnt_in, float* __restrict__ pool,
                       float* __restrict__ cntg) {
  int i = blockIdx.x * blockDim.x + threadIdx.x;
  if (i < NN) cnt_in[i] = 0;
  if (i < NG * NB) { pool[i] = 0.f; cntg[i] = 0.f; }
}

// one atomic per edge: count AND stable slot-rank in a single pass
__global__ void k_countrank(const int* __restrict__ col, int* __restrict__ cnt_in,
                            int* __restrict__ rank) {
  int e = blockIdx.x * blockDim.x + threadIdx.x;
  if (e < NE) rank[e] = atomicAdd(&cnt_in[col[e]], 1);
}

__global__ void k_scan1(const int* __restrict__ cnt_in, int* __restrict__ offs,
                        int* __restrict__ bsum) {
  __shared__ int tmp[SCAN_B];
  int t = threadIdx.x;
  int i = blockIdx.x * SCAN_B + t;
  int v = (i < NN) ? cnt_in[i] : 0;
  tmp[t] = v; __syncthreads();
  for (int off = 1; off < SCAN_B; off <<= 1) {
    int u = (t >= off) ? tmp[t - off] : 0; __syncthreads();
    tmp[t] += u; __syncthreads();
  }
  if (i < NN) offs[i] = tmp[t] - v;
  if (t == SCAN_B - 1) bsum[blockIdx.x] = tmp[t];
}

__global__ void k_scan2(const int* __restrict__ bsum, int* __restrict__ bpre) {
  __shared__ int tmp[512];
  int t = threadIdx.x;
  int v = (t < NBLK) ? bsum[t] : 0;
  tmp[t] = v; __syncthreads();
  for (int off = 1; off < 512; off <<= 1) {
    int u = (t >= off) ? tmp[t - off] : 0; __syncthreads();
    tmp[t] += u; __syncthreads();
  }
  if (t < NBLK) bpre[t] = tmp[t] - v;
}

__global__ void k_scan3(int* __restrict__ offs, const int* __restrict__ bpre) {
  int i = blockIdx.x * blockDim.x + threadIdx.x;
  if (i < NN) offs[i] += bpre[i / SCAN_B];
}

// atomic-free scatter: p = offs[dst] + rank[e]
__global__ void k_fill(const int* __restrict__ row, const int* __restrict__ col,
                       const float* __restrict__ w, const int* __restrict__ rank,
                       const int* __restrict__ offs, int2* __restrict__ elist) {
  int e = blockIdx.x * blockDim.x + threadIdx.x;
  if (e < NE) {
    int p = offs[col[e]] + rank[e];
    elist[p] = make_int2(row[e], __float_as_int(w[e]));
  }
}

// weighted in-degree (+1 self) -> dinv; xs[n][:] = dinv[n]*x[n][:]  (padded to XS)
__global__ void k_degxs(const int* __restrict__ offs, const int* __restrict__ cnt_in,
                        const int2* __restrict__ elist, const float* __restrict__ x,
                        float* __restrict__ dinv, float* __restrict__ xs) {
  int n = blockIdx.x * blockDim.x + threadIdx.x;
  if (n >= NN) return;
  int o = offs[n], cn = cnt_in[n];
  float d = 1.f;
  for (int k = 0; k < cn; ++k) d += __int_as_float(elist[o + k].y);
  float di = rsqrtf(d);
  dinv[n] = di;
  float* xr = xs + (size_t)n * XS;
#pragma unroll
  for (int f = 0; f < FIN; ++f) xr[f] = di * x[n * FIN + f];
  xr[10] = 0.f; xr[11] = 0.f;
}

// ax[c][:] = dinv_c * ( xs[c][:] + sum_e w_e * xs[src_e][:] )   — atomic-free
__global__ void k_gax(const int* __restrict__ offs, const int* __restrict__ cnt_in,
                      const int2* __restrict__ elist, const float* __restrict__ xs,
                      const float* __restrict__ dinv, float* __restrict__ ax) {
  int n = blockIdx.x * blockDim.x + threadIdx.x;
  if (n >= NN) return;
  int o = offs[n], cn = cnt_in[n];
  const float4* xc = (const float4*)(xs + (size_t)n * XS);
  float4 a0 = xc[0], a1 = xc[1], a2 = xc[2];   // self-loop (pre-scaled)
  for (int k = 0; k < cn; ++k) {
    int2 ew = elist[o + k];
    float wt = __int_as_float(ew.y);
    const float4* xr = (const float4*)(xs + (size_t)ew.x * XS);
    float4 p0 = xr[0], p1 = xr[1], p2 = xr[2];
    a0.x += wt * p0.x; a0.y += wt * p0.y; a0.z += wt * p0.z; a0.w += wt * p0.w;
    a1.x += wt * p1.x; a1.y += wt * p1.y; a1.z += wt * p1.z; a1.w += wt * p1.w;
    a2.x += wt * p2.x; a2.y += wt * p2.y; a2.z += wt * p2.z; a2.w += wt * p2.w;
  }
  float dc = dinv[n];
  float4* ar = (float4*)(ax + (size_t)n * XS);
  a0.x *= dc; a0.y *= dc; a0.z *= dc; a0.w *= dc;
  a1.x *= dc; a1.y *= dc; a1.z *= dc; a1.w *= dc;
  a2.x *= dc; a2.y *= dc;
  ar[0] = a0; ar[1] = a1; ar[2] = a2;
}

// ss[n] = dinv[n] * ( relu(ax[n] @ W1 + b1) . (W2 @ Wlin) ) ; per-graph counts
__global__ void k_s(const float* __restrict__ ax, const float* __restrict__ W1,
                    const float* __restrict__ b1, const float* __restrict__ W2,
                    const float* __restrict__ Wlin, const float* __restrict__ dinv,
                    const int* __restrict__ batch, float* __restrict__ ss,
                    float* __restrict__ cntg) {
  __shared__ float W1s[FIN * HID];
  __shared__ float b1s[HID];
  __shared__ float vs[HID];
  for (int i = threadIdx.x; i < FIN * HID; i += blockDim.x) W1s[i] = W1[i];
  if (threadIdx.x < HID) {
    b1s[threadIdx.x] = b1[threadIdx.x];
    float a = 0.f;
    for (int o = 0; o < HID; ++o) a += W2[threadIdx.x * HID + o] * Wlin[o];
    vs[threadIdx.x] = a;                       // v = W2 @ Wlin
  }
  __syncthreads();
  int n = blockIdx.x * blockDim.x + threadIdx.x;
  if (n < NN) {
    const float4* arp = (const float4*)(ax + (size_t)n * XS);
    float4 r0 = arp[0], r1 = arp[1], r2 = arp[2];
    float axr[FIN] = {r0.x, r0.y, r0.z, r0.w, r1.x, r1.y, r1.z, r1.w, r2.x, r2.y};
    float acc = 0.f;
    for (int h = 0; h < HID; ++h) {
      float t = b1s[h];
#pragma unroll
      for (int f = 0; f < FIN; ++f) t += axr[f] * W1s[f * HID + h];
      acc += fmaxf(t, 0.f) * vs[h];
    }
    ss[n] = dinv[n] * acc;
    atomicAdd(&cntg[batch[n] * NB + (threadIdx.x & (NB - 1))], 1.0f);
  }
}

// pool[g] += dinv_c * ( ss[c] + sum_e w_e * ss[src_e] )   — one atomic per node
__global__ void k_gpool(const int* __restrict__ offs, const int* __restrict__ cnt_in,
                        const int2* __restrict__ elist, const float* __restrict__ ss,
                        const float* __restrict__ dinv, const int* __restrict__ batch,
                        float* __restrict__ pool) {
  int n = blockIdx.x * blockDim.x + threadIdx.x;
  if (n >= NN) return;
  int o = offs[n], cn = cnt_in[n];
  float acc = ss[n];
  for (int k = 0; k < cn; ++k) {
    int2 ew = elist[o + k];
    acc += __int_as_float(ew.y) * ss[ew.x];
  }
  atomicAdd(&pool[batch[n] * NB + (threadIdx.x & (NB - 1))], dinv[n] * acc);
}

__global__ void k_final(const float* __restrict__ pool, const float* __restrict__ cntg,
                        const float* __restrict__ b2, const float* __restrict__ Wlin,
                        const float* __restrict__ blin, float* __restrict__ out) {
  int g = blockIdx.x * blockDim.x + threadIdx.x;
  if (g < NG) {
    float cc = blin[0];
    for (int o = 0; o < HID; ++o) cc += b2[o] * Wlin[o];
    float ps = 0.f, cs = 0.f;
    for (int b = 0; b < NB; ++b) { ps += pool[g * NB + b]; cs += cntg[g * NB + b]; }
    out[g] = ps / fmaxf(cs, 1.0f) + cc;
  }
}

// ---------------- launch ----------------

extern "C" void kernel_launch(void* const* d_in, const int* in_sizes, int n_in,
                              void* d_out, int out_size, void* d_ws, size_t ws_size,
                              hipStream_t stream) {
  const float* x     = (const float*)d_in[0];
  const int*   ei    = (const int*)d_in[1];
  const float* w     = (const float*)d_in[2];
  const int*   batch = (const int*)d_in[3];
  const float* W1    = (const float*)d_in[4];
  const float* b1    = (const float*)d_in[5];
  const float* W2    = (const float*)d_in[6];
  const float* b2    = (const float*)d_in[7];
  const float* Wlin  = (const float*)d_in[8];
  const float* blin  = (const float*)d_in[9];
  float* out = (float*)d_out;

  const int* row = ei;
  const int* col = ei + NE;

  // workspace layout (all chunks 16B-aligned)
  char* p = (char*)d_ws;
  int*   cnt_in = (int*)p;   p += sizeof(int) * NN;        // 400 KB
  int*   offs   = (int*)p;   p += sizeof(int) * NN;        // 400 KB
  int*   rank   = (int*)p;   p += sizeof(int) * NE;        // 6.4 MB (reused as ax)
  int*   bsum   = (int*)p;   p += sizeof(int) * 512;
  int*   bpre   = (int*)p;   p += sizeof(int) * 512;
  int2*  elist  = (int2*)p;  p += sizeof(int2) * NE;       // 12.8 MB
  float* dinv   = (float*)p; p += sizeof(float) * NN;
  float* xs     = (float*)p; p += sizeof(float) * (size_t)NN * XS;  // 4.8 MB
  float* ss     = (float*)p; p += sizeof(float) * NN;
  float* pool   = (float*)p; p += sizeof(float) * NG * NB;
  float* cntg   = (float*)p; p += sizeof(float) * NG * NB;
  float* ax     = (float*)rank;   // rank is dead after k_fill; ax needs 4.8 MB <= 6.4 MB

  const int B = 256;
  const int gN = (NN + B - 1) / B;   // 391
  const int gE = (NE + B - 1) / B;   // 6250

  hipLaunchKernelGGL(k_init,      dim3(gN),   dim3(B), 0, stream, cnt_in, pool, cntg);
  hipLaunchKernelGGL(k_countrank, dim3(gE),   dim3(B), 0, stream, col, cnt_in, rank);
  hipLaunchKernelGGL(k_scan1,     dim3(NBLK), dim3(SCAN_B), 0, stream, cnt_in, offs, bsum);
  hipLaunchKernelGGL(k_scan2,     dim3(1),    dim3(512), 0, stream, bsum, bpre);
  hipLaunchKernelGGL(k_scan3,     dim3(gN),   dim3(B), 0, stream, offs, bpre);
  hipLaunchKernelGGL(k_fill,      dim3(gE),   dim3(B), 0, stream, row, col, w, rank, offs, elist);
  hipLaunchKernelGGL(k_degxs,     dim3(gN),   dim3(B), 0, stream, offs, cnt_in, elist, x, dinv, xs);
  hipLaunchKernelGGL(k_gax,       dim3(gN),   dim3(B), 0, stream, offs, cnt_in, elist, xs, dinv, ax);
  hipLaunchKernelGGL(k_s,         dim3(gN),   dim3(B), 0, stream, ax, W1, b1, W2, Wlin, dinv, batch, ss, cntg);
  hipLaunchKernelGGL(k_gpool,     dim3(gN),   dim3(B), 0, stream, offs, cnt_in, elist, ss, dinv, batch, pool);
  hipLaunchKernelGGL(k_final,     dim3(1),    dim3(B), 0, stream, pool, cntg, b2, Wlin, blin, out);
}

// Round 4
// 150.361 us; speedup vs baseline: 7.0068x; 1.3215x over previous
//
#include <hip/hip_runtime.h>

#define NN 100000
#define NE 1600000
#define NG 256
#define FIN 10
#define XS 12          // padded row stride (floats) for xs/ax -> 48B, float4-aligned
#define HID 128
#define NB 64          // pool buckets per graph
#define NBKT 391       // coarse buckets of 256 nodes: ceil(NN/256)
#define FB 250         // histogram/fill blocks
#define EPB (NE / FB)  // 6400 edges per block (exact)

// ---------------- kernels ----------------

__global__ void k_init(float* __restrict__ pool, float* __restrict__ cntg) {
  int i = blockIdx.x * blockDim.x + threadIdx.x;
  if (i < NG * NB) { pool[i] = 0.f; cntg[i] = 0.f; }
}

// per-block LDS histogram over 391 buckets (bucket = dst >> 8)
__global__ void k_hist(const int* __restrict__ col, int* __restrict__ H) {
  __shared__ int h[NBKT];
  int t = threadIdx.x;
  for (int k = t; k < NBKT; k += blockDim.x) h[k] = 0;
  __syncthreads();
  int base = blockIdx.x * EPB;
  for (int i = t; i < EPB; i += blockDim.x)
    atomicAdd(&h[col[base + i] >> 8], 1);
  __syncthreads();
  for (int k = t; k < NBKT; k += blockDim.x) H[blockIdx.x * NBKT + k] = h[k];
}

// per-bucket scan across the 250 blocks: H[b][k] -> exclusive prefix; btot[k]=total
__global__ void k_scanA(int* __restrict__ H, int* __restrict__ btot) {
  __shared__ int tmp[256];
  int t = threadIdx.x;
  int k = blockIdx.x;
  int v = (t < FB) ? H[t * NBKT + k] : 0;
  tmp[t] = v; __syncthreads();
  for (int off = 1; off < 256; off <<= 1) {
    int u = (t >= off) ? tmp[t - off] : 0; __syncthreads();
    tmp[t] += u; __syncthreads();
  }
  if (t < FB) H[t * NBKT + k] = tmp[t] - v;
  if (t == 255) btot[k] = tmp[255];
}

// scan bucket totals -> bucket bases
__global__ void k_scanB(const int* __restrict__ btot, int* __restrict__ bbase) {
  __shared__ int tmp[512];
  int t = threadIdx.x;
  int v = (t < NBKT) ? btot[t] : 0;
  tmp[t] = v; __syncthreads();
  for (int off = 1; off < 512; off <<= 1) {
    int u = (t >= off) ? tmp[t - off] : 0; __syncthreads();
    tmp[t] += u; __syncthreads();
  }
  if (t < NBKT) bbase[t] = tmp[t] - v;
}

// bucket the edges: LDS cursors, semi-contiguous writes; pack (dst&255) into src bits
__global__ void k_fillb(const int* __restrict__ row, const int* __restrict__ col,
                        const float* __restrict__ w, const int* __restrict__ H,
                        const int* __restrict__ bbase, int2* __restrict__ elist) {
  __shared__ int cur[NBKT];
  int t = threadIdx.x;
  for (int k = t; k < NBKT; k += blockDim.x)
    cur[k] = bbase[k] + H[blockIdx.x * NBKT + k];
  __syncthreads();
  int base = blockIdx.x * EPB;
  for (int i = t; i < EPB; i += blockDim.x) {
    int e = base + i;
    int c = col[e];
    int p = atomicAdd(&cur[c >> 8], 1);
    elist[p] = make_int2(row[e] | ((c & 255) << 17), __float_as_int(w[e]));
  }
}

// per-bucket: node-sort edges (LDS counting sort), weighted degree -> dinv, xs = dinv*x
__global__ void k_sortdeg(const int* __restrict__ bbase, const int* __restrict__ btot,
                          const int2* __restrict__ elist, const float* __restrict__ x,
                          int2* __restrict__ elist2, int* __restrict__ offs,
                          int* __restrict__ cnt_in, float* __restrict__ dinv,
                          float* __restrict__ xs) {
  __shared__ int cnt[256];
  __shared__ float wsum[256];
  __shared__ int tmp[256];
  __shared__ int cur[256];
  int k = blockIdx.x;
  int t = threadIdx.x;
  int base = bbase[k];
  int tot = btot[k];
  cnt[t] = 0; wsum[t] = 0.f;
  __syncthreads();
  for (int i = t; i < tot; i += 256) {
    int2 ew = elist[base + i];
    int l = (ew.x >> 17) & 255;
    atomicAdd(&cnt[l], 1);
    atomicAdd(&wsum[l], __int_as_float(ew.y));
  }
  __syncthreads();
  int v = cnt[t];
  tmp[t] = v; __syncthreads();
  for (int off = 1; off < 256; off <<= 1) {
    int u = (t >= off) ? tmp[t - off] : 0; __syncthreads();
    tmp[t] += u; __syncthreads();
  }
  int excl = tmp[t] - v;
  cur[t] = base + excl;
  int n = (k << 8) + t;
  if (n < NN) {
    offs[n] = base + excl;
    cnt_in[n] = v;
    float di = rsqrtf(1.f + wsum[t]);
    dinv[n] = di;
    float* xr = xs + (size_t)n * XS;
#pragma unroll
    for (int f = 0; f < FIN; ++f) xr[f] = di * x[n * FIN + f];
    xr[10] = 0.f; xr[11] = 0.f;
  }
  __syncthreads();
  for (int i = t; i < tot; i += 256) {
    int2 ew = elist[base + i];
    int l = (ew.x >> 17) & 255;
    int p = atomicAdd(&cur[l], 1);
    elist2[p] = make_int2(ew.x & 0x1FFFF, ew.y);
  }
}

// ax[c][:] = dinv_c * ( xs[c][:] + sum_e w_e * xs[src_e][:] )   — atomic-free
__global__ void k_gax(const int* __restrict__ offs, const int* __restrict__ cnt_in,
                      const int2* __restrict__ elist2, const float* __restrict__ xs,
                      const float* __restrict__ dinv, float* __restrict__ ax) {
  int n = blockIdx.x * blockDim.x + threadIdx.x;
  if (n >= NN) return;
  int o = offs[n], cn = cnt_in[n];
  const float4* xc = (const float4*)(xs + (size_t)n * XS);
  float4 a0 = xc[0], a1 = xc[1], a2 = xc[2];   // self-loop (pre-scaled)
  for (int kk = 0; kk < cn; ++kk) {
    int2 ew = elist2[o + kk];
    float wt = __int_as_float(ew.y);
    const float4* xr = (const float4*)(xs + (size_t)ew.x * XS);
    float4 p0 = xr[0], p1 = xr[1], p2 = xr[2];
    a0.x += wt * p0.x; a0.y += wt * p0.y; a0.z += wt * p0.z; a0.w += wt * p0.w;
    a1.x += wt * p1.x; a1.y += wt * p1.y; a1.z += wt * p1.z; a1.w += wt * p1.w;
    a2.x += wt * p2.x; a2.y += wt * p2.y; a2.z += wt * p2.z; a2.w += wt * p2.w;
  }
  float dc = dinv[n];
  float4* ar = (float4*)(ax + (size_t)n * XS);
  a0.x *= dc; a0.y *= dc; a0.z *= dc; a0.w *= dc;
  a1.x *= dc; a1.y *= dc; a1.z *= dc; a1.w *= dc;
  a2.x *= dc; a2.y *= dc;
  ar[0] = a0; ar[1] = a1; ar[2] = a2;
}

// ss[n] = dinv[n] * ( relu(ax[n] @ W1 + b1) . (W2 @ Wlin) ) ; per-graph counts
__global__ void k_s(const float* __restrict__ ax, const float* __restrict__ W1,
                    const float* __restrict__ b1, const float* __restrict__ W2,
                    const float* __restrict__ Wlin, const float* __restrict__ dinv,
                    const int* __restrict__ batch, float* __restrict__ ss,
                    float* __restrict__ cntg) {
  __shared__ float W1s[FIN * HID];
  __shared__ float b1s[HID];
  __shared__ float vs[HID];
  for (int i = threadIdx.x; i < FIN * HID; i += blockDim.x) W1s[i] = W1[i];
  if (threadIdx.x < HID) {
    b1s[threadIdx.x] = b1[threadIdx.x];
    float a = 0.f;
    for (int o = 0; o < HID; ++o) a += W2[threadIdx.x * HID + o] * Wlin[o];
    vs[threadIdx.x] = a;                       // v = W2 @ Wlin
  }
  __syncthreads();
  int n = blockIdx.x * blockDim.x + threadIdx.x;
  if (n < NN) {
    const float4* arp = (const float4*)(ax + (size_t)n * XS);
    float4 r0 = arp[0], r1 = arp[1], r2 = arp[2];
    float axr[FIN] = {r0.x, r0.y, r0.z, r0.w, r1.x, r1.y, r1.z, r1.w, r2.x, r2.y};
    float acc = 0.f;
    for (int h = 0; h < HID; ++h) {
      float t = b1s[h];
#pragma unroll
      for (int f = 0; f < FIN; ++f) t += axr[f] * W1s[f * HID + h];
      acc += fmaxf(t, 0.f) * vs[h];
    }
    ss[n] = dinv[n] * acc;
    atomicAdd(&cntg[batch[n] * NB + (threadIdx.x & (NB - 1))], 1.0f);
  }
}

// pool[g] += dinv_c * ( ss[c] + sum_e w_e * ss[src_e] )   — one atomic per node
__global__ void k_gpool(const int* __restrict__ offs, const int* __restrict__ cnt_in,
                        const int2* __restrict__ elist2, const float* __restrict__ ss,
                        const float* __restrict__ dinv, const int* __restrict__ batch,
                        float* __restrict__ pool) {
  int n = blockIdx.x * blockDim.x + threadIdx.x;
  if (n >= NN) return;
  int o = offs[n], cn = cnt_in[n];
  float acc = ss[n];
  for (int kk = 0; kk < cn; ++kk) {
    int2 ew = elist2[o + kk];
    acc += __int_as_float(ew.y) * ss[ew.x];
  }
  atomicAdd(&pool[batch[n] * NB + (threadIdx.x & (NB - 1))], dinv[n] * acc);
}

__global__ void k_final(const float* __restrict__ pool, const float* __restrict__ cntg,
                        const float* __restrict__ b2, const float* __restrict__ Wlin,
                        const float* __restrict__ blin, float* __restrict__ out) {
  int g = blockIdx.x * blockDim.x + threadIdx.x;
  if (g < NG) {
    float cc = blin[0];
    for (int o = 0; o < HID; ++o) cc += b2[o] * Wlin[o];
    float ps = 0.f, cs = 0.f;
    for (int b = 0; b < NB; ++b) { ps += pool[g * NB + b]; cs += cntg[g * NB + b]; }
    out[g] = ps / fmaxf(cs, 1.0f) + cc;
  }
}

// ---------------- launch ----------------

extern "C" void kernel_launch(void* const* d_in, const int* in_sizes, int n_in,
                              void* d_out, int out_size, void* d_ws, size_t ws_size,
                              hipStream_t stream) {
  const float* x     = (const float*)d_in[0];
  const int*   ei    = (const int*)d_in[1];
  const float* w     = (const float*)d_in[2];
  const int*   batch = (const int*)d_in[3];
  const float* W1    = (const float*)d_in[4];
  const float* b1    = (const float*)d_in[5];
  const float* W2    = (const float*)d_in[6];
  const float* b2    = (const float*)d_in[7];
  const float* Wlin  = (const float*)d_in[8];
  const float* blin  = (const float*)d_in[9];
  float* out = (float*)d_out;

  const int* row = ei;
  const int* col = ei + NE;

  // workspace layout (16B-aligned chunks)
  char* p = (char*)d_ws;
  int2*  elist  = (int2*)p;  p += sizeof(int2) * NE;              // 12.8 MB (reused as ax)
  int2*  elist2 = (int2*)p;  p += sizeof(int2) * NE;              // 12.8 MB
  float* xs     = (float*)p; p += sizeof(float) * (size_t)NN * XS; // 4.8 MB
  int*   H      = (int*)p;   p += 391040;                          // FB*NBKT ints, padded
  int*   btot   = (int*)p;   p += 1600;
  int*   bbase  = (int*)p;   p += 1600;
  int*   offs   = (int*)p;   p += sizeof(int) * NN;
  int*   cnt_in = (int*)p;   p += sizeof(int) * NN;
  float* dinv   = (float*)p; p += sizeof(float) * NN;
  float* ss     = (float*)p; p += sizeof(float) * NN;
  float* pool   = (float*)p; p += sizeof(float) * NG * NB;
  float* cntg   = (float*)p; p += sizeof(float) * NG * NB;
  float* ax     = (float*)elist;   // elist dead after k_sortdeg; ax needs 4.8 <= 12.8 MB

  const int B = 256;
  const int gN = (NN + B - 1) / B;       // 391
  const int gP = (NG * NB + B - 1) / B;  // 64

  hipLaunchKernelGGL(k_init,    dim3(gP),   dim3(B), 0, stream, pool, cntg);
  hipLaunchKernelGGL(k_hist,    dim3(FB),   dim3(B), 0, stream, col, H);
  hipLaunchKernelGGL(k_scanA,   dim3(NBKT), dim3(B), 0, stream, H, btot);
  hipLaunchKernelGGL(k_scanB,   dim3(1),    dim3(512), 0, stream, btot, bbase);
  hipLaunchKernelGGL(k_fillb,   dim3(FB),   dim3(B), 0, stream, row, col, w, H, bbase, elist);
  hipLaunchKernelGGL(k_sortdeg, dim3(NBKT), dim3(B), 0, stream, bbase, btot, elist, x,
                     elist2, offs, cnt_in, dinv, xs);
  hipLaunchKernelGGL(k_gax,     dim3(gN),   dim3(B), 0, stream, offs, cnt_in, elist2, xs, dinv, ax);
  hipLaunchKernelGGL(k_s,       dim3(gN),   dim3(B), 0, stream, ax, W1, b1, W2, Wlin, dinv, batch, ss, cntg);
  hipLaunchKernelGGL(k_gpool,   dim3(gN),   dim3(B), 0, stream, offs, cnt_in, elist2, ss, dinv, batch, pool);
  hipLaunchKernelGGL(k_final,   dim3(1),    dim3(B), 0, stream, pool, cntg, b2, Wlin, blin, out);
}